// Round 1
// baseline (916.638 us; speedup 1.0000x reference)
//
#include <hip/hip_runtime.h>

#define NN 200000
#define NE 600000
#define NG 8192
#define HD 128
#define FIN 7
#define BN_EPS 1e-5f

#define CHUNK 1024
#define NB ((NN + CHUNK - 1) / CHUNK)   // 196 scan blocks

// ---------------- degree / dinv ----------------
__global__ void k_deg(const int* __restrict__ dst, int* __restrict__ deg) {
    int e = blockIdx.x * 256 + threadIdx.x;
    if (e < NE) atomicAdd(&deg[dst[e]], 1);
}

__global__ void k_dinv(const int* __restrict__ deg, float* __restrict__ dinv) {
    int i = blockIdx.x * 256 + threadIdx.x;
    if (i < NN) dinv[i] = rsqrtf((float)(deg[i] + 1));   // +1 self-loop
}

// ---------------- exclusive scan (3-phase) ----------------
__global__ void k_scan1(const int* __restrict__ deg, int* __restrict__ bsum) {
    __shared__ int sd[256];
    int t = threadIdx.x, b = blockIdx.x;
    int base = b * CHUNK + t * 4;
    int s = 0;
#pragma unroll
    for (int j = 0; j < 4; j++) { int i = base + j; if (i < NN) s += deg[i]; }
    sd[t] = s; __syncthreads();
    for (int st = 128; st > 0; st >>= 1) { if (t < st) sd[t] += sd[t + st]; __syncthreads(); }
    if (t == 0) bsum[b] = sd[0];
}

__global__ void k_scan2(int* __restrict__ bsum) {
    if (threadIdx.x == 0) {
        int run = 0;
        for (int b = 0; b < NB; b++) { int v = bsum[b]; bsum[b] = run; run += v; }
    }
}

__global__ void k_scan3(const int* __restrict__ deg, const int* __restrict__ bsum,
                        int* __restrict__ offs, int* __restrict__ cursor) {
    __shared__ int sd[256];
    int t = threadIdx.x, b = blockIdx.x;
    int base = b * CHUNK + t * 4;
    int v[4]; int s = 0;
#pragma unroll
    for (int j = 0; j < 4; j++) { int i = base + j; v[j] = (i < NN) ? deg[i] : 0; s += v[j]; }
    sd[t] = s; __syncthreads();
    for (int st = 1; st < 256; st <<= 1) {          // inclusive Hillis-Steele
        int val = (t >= st) ? sd[t - st] : 0;
        __syncthreads();
        sd[t] += val;
        __syncthreads();
    }
    int run = bsum[b] + sd[t] - s;                   // exclusive prefix for this thread
#pragma unroll
    for (int j = 0; j < 4; j++) {
        int i = base + j;
        if (i < NN) { offs[i] = run; cursor[i] = run; run += v[j]; }
    }
    if (b == 0 && t == 0) offs[NN] = NE;
}

__global__ void k_fill(const int* __restrict__ src, const int* __restrict__ dst,
                       int* __restrict__ cursor, int* __restrict__ csr) {
    int e = blockIdx.x * 256 + threadIdx.x;
    if (e < NE) {
        int d = dst[e];
        int pos = atomicAdd(&cursor[d], 1);
        csr[pos] = src[e];
    }
}

// ---------------- layer-1: aggregate raw X (7 ch), then GEMM 7->128 ----------------
__global__ void k_aggx(const float* __restrict__ x, const float* __restrict__ dinv,
                       const int* __restrict__ offs, const int* __restrict__ csr,
                       float* __restrict__ ax) {
    int gid = blockIdx.x * 256 + threadIdx.x;       // NN*8 threads
    int i = gid >> 3, f = gid & 7;
    float di = dinv[i];
    float v = (f < FIN) ? x[i * FIN + f] * di * di : 0.f;
    int o1 = offs[i], o2 = offs[i + 1];
    for (int j = o1; j < o2; j++) {
        int s = csr[j];
        if (f < FIN) v = fmaf(x[s * FIN + f], dinv[s] * di, v);
    }
    ax[i * 8 + f] = v;
}

__global__ void k_gemm1(const float* __restrict__ ax, const float* __restrict__ W0,
                        const float* __restrict__ b0,
                        const float* __restrict__ gamma, const float* __restrict__ beta,
                        const float* __restrict__ mean, const float* __restrict__ var,
                        float* __restrict__ h1) {
    int gid = blockIdx.x * 256 + threadIdx.x;       // NN*128 threads (exact)
    int i = gid >> 7, f = gid & 127;
    const float* axr = ax + i * 8;
    float acc = b0[f];
#pragma unroll
    for (int k = 0; k < FIN; k++) acc = fmaf(axr[k], W0[k * HD + f], acc);
    float sc = gamma[f] * rsqrtf(var[f] + BN_EPS);
    acc = (acc - mean[f]) * sc + beta[f];
    h1[gid] = fmaxf(acc, 0.f);
}

// ---------------- layer-2 GEMM: [N,128] x [128,128], 64-node tiles ----------------
__global__ __launch_bounds__(256) void k_gemm2(const float* __restrict__ hin,
                                               const float* __restrict__ W1,
                                               float* __restrict__ outp) {
    __shared__ float hT[128][66];                   // [k][node], pad 66 (bank spread)
    int t = threadIdx.x;
    int nbase = blockIdx.x * 64;                    // 200000 = 64*3125, exact
#pragma unroll
    for (int r = 0; r < 32; r++) {
        int l = r * 256 + t;
        int k = l & 127, node = l >> 7;
        hT[k][node] = hin[(nbase + node) * HD + k];
    }
    __syncthreads();
    int tf = t & 15, tn = t >> 4;
    int f0 = tf * 8, n0 = tn * 4;
    float acc[4][8];
#pragma unroll
    for (int a = 0; a < 4; a++)
#pragma unroll
        for (int c = 0; c < 8; c++) acc[a][c] = 0.f;

    for (int k = 0; k < 128; k++) {
        float4 wa = *reinterpret_cast<const float4*>(&W1[k * HD + f0]);
        float4 wb = *reinterpret_cast<const float4*>(&W1[k * HD + f0 + 4]);
        float hn[4];
        hn[0] = hT[k][n0]; hn[1] = hT[k][n0 + 1]; hn[2] = hT[k][n0 + 2]; hn[3] = hT[k][n0 + 3];
#pragma unroll
        for (int a = 0; a < 4; a++) {
            acc[a][0] = fmaf(hn[a], wa.x, acc[a][0]);
            acc[a][1] = fmaf(hn[a], wa.y, acc[a][1]);
            acc[a][2] = fmaf(hn[a], wa.z, acc[a][2]);
            acc[a][3] = fmaf(hn[a], wa.w, acc[a][3]);
            acc[a][4] = fmaf(hn[a], wb.x, acc[a][4]);
            acc[a][5] = fmaf(hn[a], wb.y, acc[a][5]);
            acc[a][6] = fmaf(hn[a], wb.z, acc[a][6]);
            acc[a][7] = fmaf(hn[a], wb.w, acc[a][7]);
        }
    }
#pragma unroll
    for (int a = 0; a < 4; a++) {
        int i = nbase + n0 + a;
        float4 o0 = make_float4(acc[a][0], acc[a][1], acc[a][2], acc[a][3]);
        float4 o1 = make_float4(acc[a][4], acc[a][5], acc[a][6], acc[a][7]);
        *reinterpret_cast<float4*>(&outp[i * HD + f0]) = o0;
        *reinterpret_cast<float4*>(&outp[i * HD + f0 + 4]) = o1;
    }
}

// ---------------- layer-2 aggregation (gather, float4 lanes) ----------------
__global__ void k_agg2(const float* __restrict__ h, const float* __restrict__ dinv,
                       const int* __restrict__ offs, const int* __restrict__ csr,
                       float* __restrict__ outp) {
    int gid = blockIdx.x * 256 + threadIdx.x;       // NN*32 threads (exact)
    int i = gid >> 5, q = (gid & 31) * 4;
    float di = dinv[i];
    float4 hv = *reinterpret_cast<const float4*>(&h[i * HD + q]);
    float c0 = di * di;
    float vx = hv.x * c0, vy = hv.y * c0, vz = hv.z * c0, vw = hv.w * c0;
    int o1 = offs[i], o2 = offs[i + 1];
    for (int j = o1; j < o2; j++) {
        int s = csr[j];
        float c = dinv[s] * di;
        float4 nv = *reinterpret_cast<const float4*>(&h[s * HD + q]);
        vx = fmaf(nv.x, c, vx); vy = fmaf(nv.y, c, vy);
        vz = fmaf(nv.z, c, vz); vw = fmaf(nv.w, c, vw);
    }
    float4 o = make_float4(vx, vy, vz, vw);
    *reinterpret_cast<float4*>(&outp[i * HD + q]) = o;
}

// ---------------- BN+ReLU + segmented mean-pool accumulate ----------------
__global__ void k_pool(const float* __restrict__ agg, const int* __restrict__ batch,
                       const float* __restrict__ b1,
                       const float* __restrict__ gamma, const float* __restrict__ beta,
                       const float* __restrict__ mean, const float* __restrict__ var,
                       float* __restrict__ pool) {
    int t = threadIdx.x;
    int q = (t & 31) * 4, grp = t >> 5;
    int ibase = blockIdx.x * 64 + grp * 8;          // 3125 blocks * 64 = exact
    float4 gm = *reinterpret_cast<const float4*>(&gamma[q]);
    float4 bt = *reinterpret_cast<const float4*>(&beta[q]);
    float4 mn = *reinterpret_cast<const float4*>(&mean[q]);
    float4 vr = *reinterpret_cast<const float4*>(&var[q]);
    float4 bb = *reinterpret_cast<const float4*>(&b1[q]);
    float Ax = gm.x * rsqrtf(vr.x + BN_EPS), Bx = (bb.x - mn.x) * Ax + bt.x;
    float Ay = gm.y * rsqrtf(vr.y + BN_EPS), By = (bb.y - mn.y) * Ay + bt.y;
    float Az = gm.z * rsqrtf(vr.z + BN_EPS), Bz = (bb.z - mn.z) * Az + bt.z;
    float Aw = gm.w * rsqrtf(vr.w + BN_EPS), Bw = (bb.w - mn.w) * Aw + bt.w;

    float sx = 0, sy = 0, sz = 0, sw = 0;
    int curg = -1;
    for (int n = 0; n < 8; n++) {
        int i = ibase + n;
        int g = batch[i];
        float4 v = *reinterpret_cast<const float4*>(&agg[i * HD + q]);
        float zx = fmaxf(fmaf(v.x, Ax, Bx), 0.f);
        float zy = fmaxf(fmaf(v.y, Ay, By), 0.f);
        float zz = fmaxf(fmaf(v.z, Az, Bz), 0.f);
        float zw = fmaxf(fmaf(v.w, Aw, Bw), 0.f);
        if (g != curg) {
            if (curg >= 0) {
                atomicAdd(&pool[curg * HD + q + 0], sx);
                atomicAdd(&pool[curg * HD + q + 1], sy);
                atomicAdd(&pool[curg * HD + q + 2], sz);
                atomicAdd(&pool[curg * HD + q + 3], sw);
            }
            curg = g; sx = zx; sy = zy; sz = zz; sw = zw;
        } else { sx += zx; sy += zy; sz += zz; sw += zw; }
    }
    atomicAdd(&pool[curg * HD + q + 0], sx);
    atomicAdd(&pool[curg * HD + q + 1], sy);
    atomicAdd(&pool[curg * HD + q + 2], sz);
    atomicAdd(&pool[curg * HD + q + 3], sw);
}

__global__ void k_cnt(const int* __restrict__ batch, int* __restrict__ cnt) {
    int i = blockIdx.x * 256 + threadIdx.x;
    if (i < NN) atomicAdd(&cnt[batch[i]], 1);
}

// ---------------- final MLP: [pc|ps] -> 128 relu -> 2 ----------------
__global__ __launch_bounds__(128) void k_mlp(const float* __restrict__ pc, const float* __restrict__ ps,
                                             const int* __restrict__ cc, const int* __restrict__ cs,
                                             const float* __restrict__ w1, const float* __restrict__ b1,
                                             const float* __restrict__ w2, const float* __restrict__ b2,
                                             float* __restrict__ outp) {
    __shared__ float xc[256];
    __shared__ float hb[128];
    int g = blockIdx.x, t = threadIdx.x;
    xc[t]       = pc[g * HD + t] / fmaxf((float)cc[g], 1.f);
    xc[128 + t] = ps[g * HD + t] / fmaxf((float)cs[g], 1.f);
    __syncthreads();
    float acc = b1[t];
#pragma unroll 8
    for (int k = 0; k < 256; k++) acc = fmaf(xc[k], w1[k * HD + t], acc);
    hb[t] = fmaxf(acc, 0.f);
    __syncthreads();
    if (t < 2) {
        float o = b2[t];
        for (int k = 0; k < 128; k++) o = fmaf(hb[k], w2[k * 2 + t], o);
        outp[g * 2 + t] = o;
    }
}

extern "C" void kernel_launch(void* const* d_in, const int* in_sizes, int n_in,
                              void* d_out, int out_size, void* d_ws, size_t ws_size,
                              hipStream_t stream) {
    const float* x_c      = (const float*)d_in[0];
    const int*   ei_c     = (const int*)  d_in[1];
    const int*   batch_c  = (const int*)  d_in[2];
    const float* x_s      = (const float*)d_in[3];
    const int*   ei_s     = (const int*)  d_in[4];
    const int*   batch_s  = (const int*)  d_in[5];
    const float* Wc0      = (const float*)d_in[6];
    const float* bc0      = (const float*)d_in[7];
    const float* Wc1      = (const float*)d_in[8];
    const float* bc1      = (const float*)d_in[9];
    const float* bnc_g    = (const float*)d_in[10];
    const float* bnc_b    = (const float*)d_in[11];
    const float* bnc_m    = (const float*)d_in[12];
    const float* bnc_v    = (const float*)d_in[13];
    const float* Ws0      = (const float*)d_in[14];
    const float* bs0      = (const float*)d_in[15];
    const float* Ws1      = (const float*)d_in[16];
    const float* bs1      = (const float*)d_in[17];
    const float* bns_g    = (const float*)d_in[18];
    const float* bns_b    = (const float*)d_in[19];
    const float* bns_m    = (const float*)d_in[20];
    const float* bns_v    = (const float*)d_in[21];
    const float* fc1_w    = (const float*)d_in[22];
    const float* fc1_b    = (const float*)d_in[23];
    const float* fc2_w    = (const float*)d_in[24];
    const float* fc2_b    = (const float*)d_in[25];

    char* p = (char*)d_ws;
    auto take = [&](size_t bytes) {
        void* r = (void*)p;
        p += (bytes + 255) & ~(size_t)255;
        return r;
    };
    float* bufA   = (float*)take((size_t)NN * HD * 4);   // 102.4 MB
    float* bufB   = (float*)take((size_t)NN * HD * 4);   // 102.4 MB
    float* ax     = (float*)take((size_t)NN * 8 * 4);
    int*   deg    = (int*)  take((size_t)NN * 4);
    float* dinv   = (float*)take((size_t)NN * 4);
    int*   offs   = (int*)  take((size_t)(NN + 1) * 4);
    int*   cursor = (int*)  take((size_t)NN * 4);
    int*   csr    = (int*)  take((size_t)NE * 4);
    int*   bsum   = (int*)  take((size_t)NB * 4);
    float* pool_c = (float*)take((size_t)NG * HD * 4);
    float* pool_s = (float*)take((size_t)NG * HD * 4);
    int*   cnt_c  = (int*)  take((size_t)NG * 4);
    int*   cnt_s  = (int*)  take((size_t)NG * 4);
    (void)ws_size; (void)in_sizes; (void)n_in; (void)out_size;

    hipMemsetAsync(pool_c, 0, (size_t)NG * HD * 4, stream);
    hipMemsetAsync(pool_s, 0, (size_t)NG * HD * 4, stream);
    hipMemsetAsync(cnt_c, 0, (size_t)NG * 4, stream);
    hipMemsetAsync(cnt_s, 0, (size_t)NG * 4, stream);

    auto run_branch = [&](const float* x, const int* ei, const int* batch,
                          const float* W0, const float* b0, const float* W1, const float* b1,
                          const float* g, const float* b, const float* m, const float* v,
                          float* pool, int* cnt) {
        const int* src = ei;
        const int* dst = ei + NE;
        hipMemsetAsync(deg, 0, (size_t)NN * 4, stream);
        k_deg  <<<(NE + 255) / 256, 256, 0, stream>>>(dst, deg);
        k_dinv <<<(NN + 255) / 256, 256, 0, stream>>>(deg, dinv);
        k_scan1<<<NB, 256, 0, stream>>>(deg, bsum);
        k_scan2<<<1, 64, 0, stream>>>(bsum);
        k_scan3<<<NB, 256, 0, stream>>>(deg, bsum, offs, cursor);
        k_fill <<<(NE + 255) / 256, 256, 0, stream>>>(src, dst, cursor, csr);
        k_aggx <<<NN * 8 / 256, 256, 0, stream>>>(x, dinv, offs, csr, ax);
        k_gemm1<<<NN * HD / 256, 256, 0, stream>>>(ax, W0, b0, g, b, m, v, bufA);
        k_gemm2<<<NN / 64, 256, 0, stream>>>(bufA, W1, bufB);
        k_agg2 <<<NN * 32 / 256, 256, 0, stream>>>(bufB, dinv, offs, csr, bufA);
        k_pool <<<NN / 64, 256, 0, stream>>>(bufA, batch, b1,
                                             g + HD, b + HD, m + HD, v + HD, pool);
        k_cnt  <<<(NN + 255) / 256, 256, 0, stream>>>(batch, cnt);
    };

    run_branch(x_c, ei_c, batch_c, Wc0, bc0, Wc1, bc1, bnc_g, bnc_b, bnc_m, bnc_v, pool_c, cnt_c);
    run_branch(x_s, ei_s, batch_s, Ws0, bs0, Ws1, bs1, bns_g, bns_b, bns_m, bns_v, pool_s, cnt_s);

    k_mlp<<<NG, 128, 0, stream>>>(pool_c, pool_s, cnt_c, cnt_s,
                                  fc1_w, fc1_b, fc2_w, fc2_b, (float*)d_out);
}

// Round 2
// 672.933 us; speedup vs baseline: 1.3622x; 1.3622x over previous
//
#include <hip/hip_runtime.h>

#define NN 200000
#define NE 600000
#define NG 8192
#define HD 128
#define FIN 7
#define BN_EPS 1e-5f

#define CHUNK 1024
#define NB 196          // ceil(NN / CHUNK)

// ---------------- merged degree / dinv ----------------
__global__ void k_deg2(const int* __restrict__ dstC, const int* __restrict__ dstS,
                       int* __restrict__ degC, int* __restrict__ degS) {
    int e = blockIdx.x * 256 + threadIdx.x;
    if (e < NE)            atomicAdd(&degC[dstC[e]], 1);
    else if (e < 2 * NE)   atomicAdd(&degS[dstS[e - NE]], 1);
}

__global__ void k_dinv2(const int* __restrict__ degC, const int* __restrict__ degS,
                        float* __restrict__ dinvC, float* __restrict__ dinvS) {
    int i = blockIdx.x * 256 + threadIdx.x;
    if (i < NN)            dinvC[i] = rsqrtf((float)(degC[i] + 1));
    else if (i < 2 * NN)   dinvS[i - NN] = rsqrtf((float)(degS[i - NN] + 1));
}

// ---------------- merged 3-phase exclusive scan ----------------
__global__ void k_scan1m(const int* __restrict__ degC, const int* __restrict__ degS,
                         int* __restrict__ bsumC, int* __restrict__ bsumS) {
    __shared__ int sd[256];
    int t = threadIdx.x;
    int b = blockIdx.x;
    bool sBr = b >= NB;
    int bb = sBr ? b - NB : b;
    const int* deg = sBr ? degS : degC;
    int* bsum = sBr ? bsumS : bsumC;
    int base = bb * CHUNK + t * 4;
    int s = 0;
#pragma unroll
    for (int j = 0; j < 4; j++) { int i = base + j; if (i < NN) s += deg[i]; }
    sd[t] = s; __syncthreads();
    for (int st = 128; st > 0; st >>= 1) { if (t < st) sd[t] += sd[t + st]; __syncthreads(); }
    if (t == 0) bsum[bb] = sd[0];
}

__global__ void k_scan2m(int* __restrict__ bsumC, int* __restrict__ bsumS) {
    __shared__ int sd[256];
    int* bsum = blockIdx.x ? bsumS : bsumC;
    int t = threadIdx.x;
    int v = (t < NB) ? bsum[t] : 0;
    sd[t] = v; __syncthreads();
    for (int st = 1; st < 256; st <<= 1) {
        int add = (t >= st) ? sd[t - st] : 0;
        __syncthreads();
        sd[t] += add;
        __syncthreads();
    }
    if (t < NB) bsum[t] = sd[t] - v;   // exclusive
}

__global__ void k_scan3m(const int* __restrict__ degC, const int* __restrict__ degS,
                         const int* __restrict__ bsumC, const int* __restrict__ bsumS,
                         int* __restrict__ offsC, int* __restrict__ offsS,
                         int* __restrict__ curC, int* __restrict__ curS) {
    __shared__ int sd[256];
    int t = threadIdx.x;
    int b = blockIdx.x;
    bool sBr = b >= NB;
    int bb = sBr ? b - NB : b;
    const int* deg  = sBr ? degS  : degC;
    const int* bsum = sBr ? bsumS : bsumC;
    int* offs   = sBr ? offsS : offsC;
    int* cursor = sBr ? curS  : curC;
    int base = bb * CHUNK + t * 4;
    int v[4]; int s = 0;
#pragma unroll
    for (int j = 0; j < 4; j++) { int i = base + j; v[j] = (i < NN) ? deg[i] : 0; s += v[j]; }
    sd[t] = s; __syncthreads();
    for (int st = 1; st < 256; st <<= 1) {
        int add = (t >= st) ? sd[t - st] : 0;
        __syncthreads();
        sd[t] += add;
        __syncthreads();
    }
    int run = bsum[bb] + sd[t] - s;
#pragma unroll
    for (int j = 0; j < 4; j++) {
        int i = base + j;
        if (i < NN) { offs[i] = run; cursor[i] = run; run += v[j]; }
    }
    if (bb == 0 && t == 0) offs[NN] = NE;
}

__global__ void k_fillm(const int* __restrict__ srcC, const int* __restrict__ dstC,
                        const int* __restrict__ srcS, const int* __restrict__ dstS,
                        int* __restrict__ curC, int* __restrict__ curS,
                        int* __restrict__ csrC, int* __restrict__ csrS) {
    int e = blockIdx.x * 256 + threadIdx.x;
    if (e < NE) {
        int d = dstC[e];
        int pos = atomicAdd(&curC[d], 1);
        csrC[pos] = srcC[e];
    } else if (e < 2 * NE) {
        int ee = e - NE;
        int d = dstS[ee];
        int pos = atomicAdd(&curS[d], 1);
        csrS[pos] = srcS[ee];
    }
}

// ---------------- merged layer-1 raw-X aggregation (7 ch) ----------------
__global__ void k_aggxm(const float* __restrict__ xC, const float* __restrict__ xS,
                        const float* __restrict__ dinvC, const float* __restrict__ dinvS,
                        const int* __restrict__ offsC, const int* __restrict__ offsS,
                        const int* __restrict__ csrC, const int* __restrict__ csrS,
                        float* __restrict__ axC, float* __restrict__ axS) {
    int gid = blockIdx.x * 256 + threadIdx.x;    // 2*NN*8 threads, blocks don't straddle
    bool sBr = gid >= NN * 8;
    int lid = sBr ? gid - NN * 8 : gid;
    const float* x    = sBr ? xS    : xC;
    const float* dinv = sBr ? dinvS : dinvC;
    const int*   offs = sBr ? offsS : offsC;
    const int*   csr  = sBr ? csrS  : csrC;
    float*       ax   = sBr ? axS   : axC;
    int i = lid >> 3, f = lid & 7;
    float di = dinv[i];
    float v = (f < FIN) ? x[i * FIN + f] * di * di : 0.f;
    int o1 = offs[i], o2 = offs[i + 1];
    for (int j = o1; j < o2; j++) {
        int s = csr[j];
        if (f < FIN) v = fmaf(x[s * FIN + f], dinv[s] * di, v);
    }
    ax[i * 8 + f] = v;
}

__global__ void k_cntm(const int* __restrict__ batchC, const int* __restrict__ batchS,
                       int* __restrict__ cntC, int* __restrict__ cntS) {
    int i = blockIdx.x * 256 + threadIdx.x;
    if (i < NN)            atomicAdd(&cntC[batchC[i]], 1);
    else if (i < 2 * NN)   atomicAdd(&cntS[batchS[i - NN]], 1);
}

// ---------------- fused layer-1 GEMM + BN + ReLU + layer-2 GEMM ----------------
// block: 64 nodes. stage1: h1 = relu(BN(ax @ W0 + b0)) into LDS [64][132].
// stage2: out = h1 @ W1, thread = 8 nodes x 4 features.
__global__ __launch_bounds__(256, 4) void k_gemm12(
    const float* __restrict__ ax,
    const float* __restrict__ W0, const float* __restrict__ b0,
    const float* __restrict__ gamma, const float* __restrict__ beta,
    const float* __restrict__ mean, const float* __restrict__ var,
    const float* __restrict__ W1,
    float* __restrict__ outp)
{
    __shared__ float h1[64][132];
    int t = threadIdx.x;
    int nbase = blockIdx.x * 64;                 // 3125 blocks exact

    // ---- stage 1 ----
    {
        int node = t & 63, fq = t >> 6;          // f range: fq*32 .. fq*32+31
        float4 v0 = *reinterpret_cast<const float4*>(&ax[(size_t)(nbase + node) * 8]);
        float4 v1 = *reinterpret_cast<const float4*>(&ax[(size_t)(nbase + node) * 8 + 4]);
        float axr[7] = { v0.x, v0.y, v0.z, v0.w, v1.x, v1.y, v1.z };
#pragma unroll
        for (int jj = 0; jj < 8; jj++) {
            int f = fq * 32 + jj * 4;
            float4 acc = *reinterpret_cast<const float4*>(&b0[f]);
#pragma unroll
            for (int k = 0; k < FIN; k++) {
                float4 w = *reinterpret_cast<const float4*>(&W0[k * HD + f]);
                acc.x = fmaf(axr[k], w.x, acc.x);
                acc.y = fmaf(axr[k], w.y, acc.y);
                acc.z = fmaf(axr[k], w.z, acc.z);
                acc.w = fmaf(axr[k], w.w, acc.w);
            }
            float4 gm = *reinterpret_cast<const float4*>(&gamma[f]);
            float4 bt = *reinterpret_cast<const float4*>(&beta[f]);
            float4 mn = *reinterpret_cast<const float4*>(&mean[f]);
            float4 vr = *reinterpret_cast<const float4*>(&var[f]);
            float Ax = gm.x * rsqrtf(vr.x + BN_EPS);
            float Ay = gm.y * rsqrtf(vr.y + BN_EPS);
            float Az = gm.z * rsqrtf(vr.z + BN_EPS);
            float Aw = gm.w * rsqrtf(vr.w + BN_EPS);
            h1[node][f + 0] = fmaxf((acc.x - mn.x) * Ax + bt.x, 0.f);
            h1[node][f + 1] = fmaxf((acc.y - mn.y) * Ay + bt.y, 0.f);
            h1[node][f + 2] = fmaxf((acc.z - mn.z) * Az + bt.z, 0.f);
            h1[node][f + 3] = fmaxf((acc.w - mn.w) * Aw + bt.w, 0.f);
        }
    }
    __syncthreads();

    // ---- stage 2 ----
    int nf = t & 31, ng = t >> 5;
    int f0 = nf * 4, n0 = ng * 8;
    float acc[8][4];
#pragma unroll
    for (int a = 0; a < 8; a++)
#pragma unroll
        for (int c = 0; c < 4; c++) acc[a][c] = 0.f;

    for (int k = 0; k < 128; k += 4) {
        float ha[8][4];
#pragma unroll
        for (int a = 0; a < 8; a++) {
            float4 hv = *reinterpret_cast<const float4*>(&h1[n0 + a][k]);
            ha[a][0] = hv.x; ha[a][1] = hv.y; ha[a][2] = hv.z; ha[a][3] = hv.w;
        }
#pragma unroll
        for (int j = 0; j < 4; j++) {
            float4 w = *reinterpret_cast<const float4*>(&W1[(k + j) * HD + f0]);
#pragma unroll
            for (int a = 0; a < 8; a++) {
                acc[a][0] = fmaf(ha[a][j], w.x, acc[a][0]);
                acc[a][1] = fmaf(ha[a][j], w.y, acc[a][1]);
                acc[a][2] = fmaf(ha[a][j], w.z, acc[a][2]);
                acc[a][3] = fmaf(ha[a][j], w.w, acc[a][3]);
            }
        }
    }
#pragma unroll
    for (int a = 0; a < 8; a++) {
        *reinterpret_cast<float4*>(&outp[(size_t)(nbase + n0 + a) * HD + f0]) =
            make_float4(acc[a][0], acc[a][1], acc[a][2], acc[a][3]);
    }
}

// ---------------- fused layer-2 aggregation + BN + ReLU + mean-pool ----------------
__global__ __launch_bounds__(256) void k_aggpool(
    const float* __restrict__ h, const float* __restrict__ dinv,
    const int* __restrict__ offs, const int* __restrict__ csr,
    const int* __restrict__ batch, const float* __restrict__ b1,
    const float* __restrict__ gamma, const float* __restrict__ beta,
    const float* __restrict__ mean, const float* __restrict__ var,
    float* __restrict__ pool)
{
    int t = threadIdx.x;
    int q = (t & 31) * 4;
    int ibase = blockIdx.x * 64 + (t >> 5) * 8;  // 3125 blocks * 64 nodes
    float4 gm = *reinterpret_cast<const float4*>(&gamma[q]);
    float4 bt = *reinterpret_cast<const float4*>(&beta[q]);
    float4 mn = *reinterpret_cast<const float4*>(&mean[q]);
    float4 vr = *reinterpret_cast<const float4*>(&var[q]);
    float4 bb = *reinterpret_cast<const float4*>(&b1[q]);
    float Ax = gm.x * rsqrtf(vr.x + BN_EPS), Bx = (bb.x - mn.x) * Ax + bt.x;
    float Ay = gm.y * rsqrtf(vr.y + BN_EPS), By = (bb.y - mn.y) * Ay + bt.y;
    float Az = gm.z * rsqrtf(vr.z + BN_EPS), Bz = (bb.z - mn.z) * Az + bt.z;
    float Aw = gm.w * rsqrtf(vr.w + BN_EPS), Bw = (bb.w - mn.w) * Aw + bt.w;

    float sx = 0, sy = 0, sz = 0, sw = 0;
    int curg = -1;
    for (int n = 0; n < 8; n++) {
        int i = ibase + n;
        int g = batch[i];
        float di = dinv[i];
        float4 hv = *reinterpret_cast<const float4*>(&h[(size_t)i * HD + q]);
        float c0 = di * di;
        float vx = hv.x * c0, vy = hv.y * c0, vz = hv.z * c0, vw = hv.w * c0;
        int o1 = offs[i], o2 = offs[i + 1];
        for (int j = o1; j < o2; j++) {
            int s = csr[j];
            float c = dinv[s] * di;
            float4 nv = *reinterpret_cast<const float4*>(&h[(size_t)s * HD + q]);
            vx = fmaf(nv.x, c, vx); vy = fmaf(nv.y, c, vy);
            vz = fmaf(nv.z, c, vz); vw = fmaf(nv.w, c, vw);
        }
        float zx = fmaxf(fmaf(vx, Ax, Bx), 0.f);
        float zy = fmaxf(fmaf(vy, Ay, By), 0.f);
        float zz = fmaxf(fmaf(vz, Az, Bz), 0.f);
        float zw = fmaxf(fmaf(vw, Aw, Bw), 0.f);
        if (g != curg) {
            if (curg >= 0) {
                atomicAdd(&pool[curg * HD + q + 0], sx);
                atomicAdd(&pool[curg * HD + q + 1], sy);
                atomicAdd(&pool[curg * HD + q + 2], sz);
                atomicAdd(&pool[curg * HD + q + 3], sw);
            }
            curg = g; sx = zx; sy = zy; sz = zz; sw = zw;
        } else { sx += zx; sy += zy; sz += zz; sw += zw; }
    }
    atomicAdd(&pool[curg * HD + q + 0], sx);
    atomicAdd(&pool[curg * HD + q + 1], sy);
    atomicAdd(&pool[curg * HD + q + 2], sz);
    atomicAdd(&pool[curg * HD + q + 3], sw);
}

// ---------------- final MLP, 4 graphs per block ----------------
#define GPB 4
__global__ __launch_bounds__(128) void k_mlp(
    const float* __restrict__ pc, const float* __restrict__ ps,
    const int* __restrict__ cc, const int* __restrict__ cs,
    const float* __restrict__ w1, const float* __restrict__ b1,
    const float* __restrict__ w2, const float* __restrict__ b2,
    float* __restrict__ outp)
{
    __shared__ float xc[GPB][256];
    __shared__ float hb[GPB][128];
    int t = threadIdx.x;
    int g0 = blockIdx.x * GPB;
#pragma unroll
    for (int gg = 0; gg < GPB; gg++) {
        int g = g0 + gg;
        xc[gg][t]       = pc[g * HD + t] / fmaxf((float)cc[g], 1.f);
        xc[gg][128 + t] = ps[g * HD + t] / fmaxf((float)cs[g], 1.f);
    }
    __syncthreads();
    float acc[GPB];
#pragma unroll
    for (int gg = 0; gg < GPB; gg++) acc[gg] = b1[t];
#pragma unroll 4
    for (int k = 0; k < 256; k++) {
        float w = w1[k * HD + t];
#pragma unroll
        for (int gg = 0; gg < GPB; gg++) acc[gg] = fmaf(xc[gg][k], w, acc[gg]);
    }
#pragma unroll
    for (int gg = 0; gg < GPB; gg++) hb[gg][t] = fmaxf(acc[gg], 0.f);
    __syncthreads();
    if (t < GPB * 2) {
        int gg = t >> 1, o = t & 1;
        float v = b2[o];
        for (int k = 0; k < 128; k++) v = fmaf(hb[gg][k], w2[k * 2 + o], v);
        outp[(size_t)(g0 + gg) * 2 + o] = v;
    }
}

extern "C" void kernel_launch(void* const* d_in, const int* in_sizes, int n_in,
                              void* d_out, int out_size, void* d_ws, size_t ws_size,
                              hipStream_t stream) {
    const float* x_c      = (const float*)d_in[0];
    const int*   ei_c     = (const int*)  d_in[1];
    const int*   batch_c  = (const int*)  d_in[2];
    const float* x_s      = (const float*)d_in[3];
    const int*   ei_s     = (const int*)  d_in[4];
    const int*   batch_s  = (const int*)  d_in[5];
    const float* Wc0      = (const float*)d_in[6];
    const float* bc0      = (const float*)d_in[7];
    const float* Wc1      = (const float*)d_in[8];
    const float* bc1      = (const float*)d_in[9];
    const float* bnc_g    = (const float*)d_in[10];
    const float* bnc_b    = (const float*)d_in[11];
    const float* bnc_m    = (const float*)d_in[12];
    const float* bnc_v    = (const float*)d_in[13];
    const float* Ws0      = (const float*)d_in[14];
    const float* bs0      = (const float*)d_in[15];
    const float* Ws1      = (const float*)d_in[16];
    const float* bs1      = (const float*)d_in[17];
    const float* bns_g    = (const float*)d_in[18];
    const float* bns_b    = (const float*)d_in[19];
    const float* bns_m    = (const float*)d_in[20];
    const float* bns_v    = (const float*)d_in[21];
    const float* fc1_w    = (const float*)d_in[22];
    const float* fc1_b    = (const float*)d_in[23];
    const float* fc2_w    = (const float*)d_in[24];
    const float* fc2_b    = (const float*)d_in[25];

    char* p = (char*)d_ws;
    auto take = [&](size_t bytes) {
        void* r = (void*)p;
        p += (bytes + 255) & ~(size_t)255;
        return r;
    };
    float* h2     = (float*)take((size_t)NN * HD * 4);     // 102.4 MB (shared by branches)
    float* ax_c   = (float*)take((size_t)NN * 8 * 4);
    float* ax_s   = (float*)take((size_t)NN * 8 * 4);
    int*   deg_c  = (int*)  take((size_t)NN * 4);          // contiguous with deg_s (one memset)
    int*   deg_s  = (int*)  take((size_t)NN * 4);
    float* dinv_c = (float*)take((size_t)NN * 4);
    float* dinv_s = (float*)take((size_t)NN * 4);
    int*   offs_c = (int*)  take((size_t)(NN + 1) * 4);
    int*   offs_s = (int*)  take((size_t)(NN + 1) * 4);
    int*   cur_c  = (int*)  take((size_t)NN * 4);
    int*   cur_s  = (int*)  take((size_t)NN * 4);
    int*   csr_c  = (int*)  take((size_t)NE * 4);
    int*   csr_s  = (int*)  take((size_t)NE * 4);
    int*   bsum_c = (int*)  take((size_t)NB * 4);
    int*   bsum_s = (int*)  take((size_t)NB * 4);
    float* pool_c = (float*)take((size_t)NG * HD * 4);     // contiguous region: pool_c..cnt_s
    float* pool_s = (float*)take((size_t)NG * HD * 4);
    int*   cnt_c  = (int*)  take((size_t)NG * 4);
    int*   cnt_s  = (int*)  take((size_t)NG * 4);
    (void)ws_size; (void)in_sizes; (void)n_in; (void)out_size;

    hipMemsetAsync(deg_c, 0, (size_t)2 * NN * 4, stream);                       // deg_c + deg_s
    hipMemsetAsync(pool_c, 0, ((size_t)2 * NG * HD + 2 * NG) * 4, stream);      // pools + cnts

    const int* src_c = ei_c;           const int* dst_c = ei_c + NE;
    const int* src_s = ei_s;           const int* dst_s = ei_s + NE;

    // ---- merged prep (both branches in each launch) ----
    k_deg2  <<<(2 * NE + 255) / 256, 256, 0, stream>>>(dst_c, dst_s, deg_c, deg_s);
    k_dinv2 <<<(2 * NN + 255) / 256, 256, 0, stream>>>(deg_c, deg_s, dinv_c, dinv_s);
    k_scan1m<<<2 * NB, 256, 0, stream>>>(deg_c, deg_s, bsum_c, bsum_s);
    k_scan2m<<<2, 256, 0, stream>>>(bsum_c, bsum_s);
    k_scan3m<<<2 * NB, 256, 0, stream>>>(deg_c, deg_s, bsum_c, bsum_s,
                                         offs_c, offs_s, cur_c, cur_s);
    k_fillm <<<(2 * NE + 255) / 256, 256, 0, stream>>>(src_c, dst_c, src_s, dst_s,
                                                       cur_c, cur_s, csr_c, csr_s);
    k_aggxm <<<2 * NN * 8 / 256, 256, 0, stream>>>(x_c, x_s, dinv_c, dinv_s,
                                                   offs_c, offs_s, csr_c, csr_s, ax_c, ax_s);
    k_cntm  <<<(2 * NN + 255) / 256, 256, 0, stream>>>(batch_c, batch_s, cnt_c, cnt_s);

    // ---- branch c: fused gemm + fused agg/pool ----
    k_gemm12 <<<NN / 64, 256, 0, stream>>>(ax_c, Wc0, bc0, bnc_g, bnc_b, bnc_m, bnc_v, Wc1, h2);
    k_aggpool<<<NN / 64, 256, 0, stream>>>(h2, dinv_c, offs_c, csr_c, batch_c, bc1,
                                           bnc_g + HD, bnc_b + HD, bnc_m + HD, bnc_v + HD, pool_c);
    // ---- branch s ----
    k_gemm12 <<<NN / 64, 256, 0, stream>>>(ax_s, Ws0, bs0, bns_g, bns_b, bns_m, bns_v, Ws1, h2);
    k_aggpool<<<NN / 64, 256, 0, stream>>>(h2, dinv_s, offs_s, csr_s, batch_s, bs1,
                                           bns_g + HD, bns_b + HD, bns_m + HD, bns_v + HD, pool_s);

    k_mlp<<<NG / GPB, 128, 0, stream>>>(pool_c, pool_s, cnt_c, cnt_s,
                                        fc1_w, fc1_b, fc2_w, fc2_b, (float*)d_out);
}

// Round 3
// 672.124 us; speedup vs baseline: 1.3638x; 1.0012x over previous
//
#include <hip/hip_runtime.h>

#define NN 200000
#define NE 600000
#define NG 8192
#define HD 128
#define FIN 7
#define BN_EPS 1e-5f

#define CHUNK 1024
#define NB 196          // ceil(NN / CHUNK)

// ---------------- merged degree ----------------
__global__ void k_deg2(const int* __restrict__ dstC, const int* __restrict__ dstS,
                       int* __restrict__ degC, int* __restrict__ degS) {
    int e = blockIdx.x * 256 + threadIdx.x;
    if (e < NE)            atomicAdd(&degC[dstC[e]], 1);
    else if (e < 2 * NE)   atomicAdd(&degS[dstS[e - NE]], 1);
}

// ---------------- merged 3-phase exclusive scan (dinv folded into phase 1) ----------------
__global__ void k_scan1m(const int* __restrict__ degC, const int* __restrict__ degS,
                         int* __restrict__ bsumC, int* __restrict__ bsumS,
                         float* __restrict__ dinvC, float* __restrict__ dinvS) {
    __shared__ int sd[256];
    int t = threadIdx.x;
    int b = blockIdx.x;
    bool sBr = b >= NB;
    int bb = sBr ? b - NB : b;
    const int* deg = sBr ? degS : degC;
    float* dinv = sBr ? dinvS : dinvC;
    int* bsum = sBr ? bsumS : bsumC;
    int base = bb * CHUNK + t * 4;
    int s = 0;
#pragma unroll
    for (int j = 0; j < 4; j++) {
        int i = base + j;
        if (i < NN) {
            int d = deg[i];
            s += d;
            dinv[i] = rsqrtf((float)(d + 1));
        }
    }
    sd[t] = s; __syncthreads();
    for (int st = 128; st > 0; st >>= 1) { if (t < st) sd[t] += sd[t + st]; __syncthreads(); }
    if (t == 0) bsum[bb] = sd[0];
}

__global__ void k_scan2m(int* __restrict__ bsumC, int* __restrict__ bsumS) {
    __shared__ int sd[256];
    int* bsum = blockIdx.x ? bsumS : bsumC;
    int t = threadIdx.x;
    int v = (t < NB) ? bsum[t] : 0;
    sd[t] = v; __syncthreads();
    for (int st = 1; st < 256; st <<= 1) {
        int add = (t >= st) ? sd[t - st] : 0;
        __syncthreads();
        sd[t] += add;
        __syncthreads();
    }
    if (t < NB) bsum[t] = sd[t] - v;   // exclusive
}

__global__ void k_scan3m(const int* __restrict__ degC, const int* __restrict__ degS,
                         const int* __restrict__ bsumC, const int* __restrict__ bsumS,
                         int* __restrict__ offsC, int* __restrict__ offsS,
                         int* __restrict__ curC, int* __restrict__ curS) {
    __shared__ int sd[256];
    int t = threadIdx.x;
    int b = blockIdx.x;
    bool sBr = b >= NB;
    int bb = sBr ? b - NB : b;
    const int* deg  = sBr ? degS  : degC;
    const int* bsum = sBr ? bsumS : bsumC;
    int* offs   = sBr ? offsS : offsC;
    int* cursor = sBr ? curS  : curC;
    int base = bb * CHUNK + t * 4;
    int v[4]; int s = 0;
#pragma unroll
    for (int j = 0; j < 4; j++) { int i = base + j; v[j] = (i < NN) ? deg[i] : 0; s += v[j]; }
    sd[t] = s; __syncthreads();
    for (int st = 1; st < 256; st <<= 1) {
        int add = (t >= st) ? sd[t - st] : 0;
        __syncthreads();
        sd[t] += add;
        __syncthreads();
    }
    int run = bsum[bb] + sd[t] - s;
#pragma unroll
    for (int j = 0; j < 4; j++) {
        int i = base + j;
        if (i < NN) { offs[i] = run; cursor[i] = run; run += v[j]; }
    }
    if (bb == 0 && t == 0) offs[NN] = NE;
}

__global__ void k_fillm(const int* __restrict__ srcC, const int* __restrict__ dstC,
                        const int* __restrict__ srcS, const int* __restrict__ dstS,
                        int* __restrict__ curC, int* __restrict__ curS,
                        int* __restrict__ csrC, int* __restrict__ csrS) {
    int e = blockIdx.x * 256 + threadIdx.x;
    if (e < NE) {
        int d = dstC[e];
        int pos = atomicAdd(&curC[d], 1);
        csrC[pos] = srcC[e];
    } else if (e < 2 * NE) {
        int ee = e - NE;
        int d = dstS[ee];
        int pos = atomicAdd(&curS[d], 1);
        csrS[pos] = srcS[ee];
    }
}

// ---------------- merged layer-1 raw-X aggregation (7 ch) ----------------
__global__ void k_aggxm(const float* __restrict__ xC, const float* __restrict__ xS,
                        const float* __restrict__ dinvC, const float* __restrict__ dinvS,
                        const int* __restrict__ offsC, const int* __restrict__ offsS,
                        const int* __restrict__ csrC, const int* __restrict__ csrS,
                        float* __restrict__ axC, float* __restrict__ axS) {
    int gid = blockIdx.x * 256 + threadIdx.x;    // 2*NN*8 threads, blocks don't straddle
    bool sBr = gid >= NN * 8;
    int lid = sBr ? gid - NN * 8 : gid;
    const float* x    = sBr ? xS    : xC;
    const float* dinv = sBr ? dinvS : dinvC;
    const int*   offs = sBr ? offsS : offsC;
    const int*   csr  = sBr ? csrS  : csrC;
    float*       ax   = sBr ? axS   : axC;
    int i = lid >> 3, f = lid & 7;
    float di = dinv[i];
    float v = (f < FIN) ? x[i * FIN + f] * di * di : 0.f;
    int o1 = offs[i], o2 = offs[i + 1];
    for (int j = o1; j < o2; j++) {
        int s = csr[j];
        if (f < FIN) v = fmaf(x[s * FIN + f], dinv[s] * di, v);
    }
    ax[i * 8 + f] = v;
}

__global__ void k_cntm(const int* __restrict__ batchC, const int* __restrict__ batchS,
                       int* __restrict__ cntC, int* __restrict__ cntS) {
    int i = blockIdx.x * 256 + threadIdx.x;
    if (i < NN)            atomicAdd(&cntC[batchC[i]], 1);
    else if (i < 2 * NN)   atomicAdd(&cntS[batchS[i - NN]], 1);
}

// ---------------- layer-1 GEMM + BN + ReLU (streaming, writes h1) ----------------
__global__ __launch_bounds__(256) void k_gemm1m(
    const float* __restrict__ ax,
    const float* __restrict__ W0, const float* __restrict__ b0,
    const float* __restrict__ gamma, const float* __restrict__ beta,
    const float* __restrict__ mean, const float* __restrict__ var,
    float* __restrict__ h1)
{
    int gid = blockIdx.x * 256 + threadIdx.x;   // NN*32 threads, exact (25000 blocks)
    int i = gid >> 5, q = (gid & 31) * 4;
    float4 a0 = *reinterpret_cast<const float4*>(&ax[(size_t)i * 8]);
    float4 a1 = *reinterpret_cast<const float4*>(&ax[(size_t)i * 8 + 4]);
    float axr[7] = { a0.x, a0.y, a0.z, a0.w, a1.x, a1.y, a1.z };
    float4 acc = *reinterpret_cast<const float4*>(&b0[q]);
#pragma unroll
    for (int k = 0; k < FIN; k++) {
        float4 w = *reinterpret_cast<const float4*>(&W0[k * HD + q]);
        acc.x = fmaf(axr[k], w.x, acc.x);
        acc.y = fmaf(axr[k], w.y, acc.y);
        acc.z = fmaf(axr[k], w.z, acc.z);
        acc.w = fmaf(axr[k], w.w, acc.w);
    }
    float4 gm = *reinterpret_cast<const float4*>(&gamma[q]);
    float4 bt = *reinterpret_cast<const float4*>(&beta[q]);
    float4 mn = *reinterpret_cast<const float4*>(&mean[q]);
    float4 vr = *reinterpret_cast<const float4*>(&var[q]);
    float4 o;
    o.x = fmaxf((acc.x - mn.x) * (gm.x * rsqrtf(vr.x + BN_EPS)) + bt.x, 0.f);
    o.y = fmaxf((acc.y - mn.y) * (gm.y * rsqrtf(vr.y + BN_EPS)) + bt.y, 0.f);
    o.z = fmaxf((acc.z - mn.z) * (gm.z * rsqrtf(vr.z + BN_EPS)) + bt.z, 0.f);
    o.w = fmaxf((acc.w - mn.w) * (gm.w * rsqrtf(vr.w + BN_EPS)) + bt.w, 0.f);
    *reinterpret_cast<float4*>(&h1[(size_t)i * HD + q]) = o;
}

// ---------------- fused: gather agg(h1) -> LDS, GEMM W1, BN+ReLU, mean-pool ----------------
// uses agg(h1 @ W1) == agg(h1) @ W1 (aggregation is linear)
__global__ __launch_bounds__(256, 4) void k_agp(
    const float* __restrict__ h1, const float* __restrict__ dinv,
    const int* __restrict__ offs, const int* __restrict__ csr,
    const int* __restrict__ batch,
    const float* __restrict__ W1, const float* __restrict__ b1,
    const float* __restrict__ gamma, const float* __restrict__ beta,
    const float* __restrict__ mean, const float* __restrict__ var,
    float* __restrict__ pool)
{
    __shared__ float g2[64][132];
    int t = threadIdx.x;
    int nbase = blockIdx.x * 64;                 // 3125 blocks exact
    int q = (t & 31) * 4;                        // feature quad
    int ng = t >> 5;                             // node group (8 nodes)

    // ---- phase 1: gather agg(h1) tile into LDS ----
#pragma unroll
    for (int n = 0; n < 8; n++) {
        int i = nbase + ng * 8 + n;
        float di = dinv[i];
        float4 hv = *reinterpret_cast<const float4*>(&h1[(size_t)i * HD + q]);
        float c0 = di * di;
        float vx = hv.x * c0, vy = hv.y * c0, vz = hv.z * c0, vw = hv.w * c0;
        int o1 = offs[i], o2 = offs[i + 1];
        for (int j = o1; j < o2; j++) {
            int s = csr[j];
            float c = dinv[s] * di;
            float4 nv = *reinterpret_cast<const float4*>(&h1[(size_t)s * HD + q]);
            vx = fmaf(nv.x, c, vx); vy = fmaf(nv.y, c, vy);
            vz = fmaf(nv.z, c, vz); vw = fmaf(nv.w, c, vw);
        }
        *reinterpret_cast<float4*>(&g2[ng * 8 + n][q]) = make_float4(vx, vy, vz, vw);
    }
    __syncthreads();

    // ---- phase 2: GEMM (64x128 @ 128x128), thread = 8 nodes x 4 features ----
    int f0 = q, n0 = ng * 8;
    float acc[8][4];
#pragma unroll
    for (int a = 0; a < 8; a++)
#pragma unroll
        for (int c = 0; c < 4; c++) acc[a][c] = 0.f;

    for (int k = 0; k < 128; k += 4) {
        float ha[8][4];
#pragma unroll
        for (int a = 0; a < 8; a++) {
            float4 hv = *reinterpret_cast<const float4*>(&g2[n0 + a][k]);
            ha[a][0] = hv.x; ha[a][1] = hv.y; ha[a][2] = hv.z; ha[a][3] = hv.w;
        }
#pragma unroll
        for (int j = 0; j < 4; j++) {
            float4 w = *reinterpret_cast<const float4*>(&W1[(k + j) * HD + f0]);
#pragma unroll
            for (int a = 0; a < 8; a++) {
                acc[a][0] = fmaf(ha[a][j], w.x, acc[a][0]);
                acc[a][1] = fmaf(ha[a][j], w.y, acc[a][1]);
                acc[a][2] = fmaf(ha[a][j], w.z, acc[a][2]);
                acc[a][3] = fmaf(ha[a][j], w.w, acc[a][3]);
            }
        }
    }

    // ---- phase 3: BN + ReLU + segmented mean-pool (batch sorted) ----
    float4 gm = *reinterpret_cast<const float4*>(&gamma[f0]);
    float4 bt = *reinterpret_cast<const float4*>(&beta[f0]);
    float4 mn = *reinterpret_cast<const float4*>(&mean[f0]);
    float4 vr = *reinterpret_cast<const float4*>(&var[f0]);
    float4 bb = *reinterpret_cast<const float4*>(&b1[f0]);
    float Ax = gm.x * rsqrtf(vr.x + BN_EPS), Bx = (bb.x - mn.x) * Ax + bt.x;
    float Ay = gm.y * rsqrtf(vr.y + BN_EPS), By = (bb.y - mn.y) * Ay + bt.y;
    float Az = gm.z * rsqrtf(vr.z + BN_EPS), Bz = (bb.z - mn.z) * Az + bt.z;
    float Aw = gm.w * rsqrtf(vr.w + BN_EPS), Bw = (bb.w - mn.w) * Aw + bt.w;

    float sx = 0, sy = 0, sz = 0, sw = 0;
    int curg = -1;
#pragma unroll
    for (int a = 0; a < 8; a++) {
        int i = nbase + n0 + a;
        int g = batch[i];
        float zx = fmaxf(fmaf(acc[a][0], Ax, Bx), 0.f);
        float zy = fmaxf(fmaf(acc[a][1], Ay, By), 0.f);
        float zz = fmaxf(fmaf(acc[a][2], Az, Bz), 0.f);
        float zw = fmaxf(fmaf(acc[a][3], Aw, Bw), 0.f);
        if (g != curg) {
            if (curg >= 0) {
                atomicAdd(&pool[curg * HD + f0 + 0], sx);
                atomicAdd(&pool[curg * HD + f0 + 1], sy);
                atomicAdd(&pool[curg * HD + f0 + 2], sz);
                atomicAdd(&pool[curg * HD + f0 + 3], sw);
            }
            curg = g; sx = zx; sy = zy; sz = zz; sw = zw;
        } else { sx += zx; sy += zy; sz += zz; sw += zw; }
    }
    atomicAdd(&pool[curg * HD + f0 + 0], sx);
    atomicAdd(&pool[curg * HD + f0 + 1], sy);
    atomicAdd(&pool[curg * HD + f0 + 2], sz);
    atomicAdd(&pool[curg * HD + f0 + 3], sw);
}

// ---------------- final MLP, 4 graphs per block ----------------
#define GPB 4
__global__ __launch_bounds__(128) void k_mlp(
    const float* __restrict__ pc, const float* __restrict__ ps,
    const int* __restrict__ cc, const int* __restrict__ cs,
    const float* __restrict__ w1, const float* __restrict__ b1,
    const float* __restrict__ w2, const float* __restrict__ b2,
    float* __restrict__ outp)
{
    __shared__ float xc[GPB][256];
    __shared__ float hb[GPB][128];
    int t = threadIdx.x;
    int g0 = blockIdx.x * GPB;
#pragma unroll
    for (int gg = 0; gg < GPB; gg++) {
        int g = g0 + gg;
        xc[gg][t]       = pc[g * HD + t] / fmaxf((float)cc[g], 1.f);
        xc[gg][128 + t] = ps[g * HD + t] / fmaxf((float)cs[g], 1.f);
    }
    __syncthreads();
    float acc[GPB];
#pragma unroll
    for (int gg = 0; gg < GPB; gg++) acc[gg] = b1[t];
#pragma unroll 4
    for (int k = 0; k < 256; k++) {
        float w = w1[k * HD + t];
#pragma unroll
        for (int gg = 0; gg < GPB; gg++) acc[gg] = fmaf(xc[gg][k], w, acc[gg]);
    }
#pragma unroll
    for (int gg = 0; gg < GPB; gg++) hb[gg][t] = fmaxf(acc[gg], 0.f);
    __syncthreads();
    if (t < GPB * 2) {
        int gg = t >> 1, o = t & 1;
        float v = b2[o];
        for (int k = 0; k < 128; k++) v = fmaf(hb[gg][k], w2[k * 2 + o], v);
        outp[(size_t)(g0 + gg) * 2 + o] = v;
    }
}

extern "C" void kernel_launch(void* const* d_in, const int* in_sizes, int n_in,
                              void* d_out, int out_size, void* d_ws, size_t ws_size,
                              hipStream_t stream) {
    const float* x_c      = (const float*)d_in[0];
    const int*   ei_c     = (const int*)  d_in[1];
    const int*   batch_c  = (const int*)  d_in[2];
    const float* x_s      = (const float*)d_in[3];
    const int*   ei_s     = (const int*)  d_in[4];
    const int*   batch_s  = (const int*)  d_in[5];
    const float* Wc0      = (const float*)d_in[6];
    const float* bc0      = (const float*)d_in[7];
    const float* Wc1      = (const float*)d_in[8];
    const float* bc1      = (const float*)d_in[9];
    const float* bnc_g    = (const float*)d_in[10];
    const float* bnc_b    = (const float*)d_in[11];
    const float* bnc_m    = (const float*)d_in[12];
    const float* bnc_v    = (const float*)d_in[13];
    const float* Ws0      = (const float*)d_in[14];
    const float* bs0      = (const float*)d_in[15];
    const float* Ws1      = (const float*)d_in[16];
    const float* bs1      = (const float*)d_in[17];
    const float* bns_g    = (const float*)d_in[18];
    const float* bns_b    = (const float*)d_in[19];
    const float* bns_m    = (const float*)d_in[20];
    const float* bns_v    = (const float*)d_in[21];
    const float* fc1_w    = (const float*)d_in[22];
    const float* fc1_b    = (const float*)d_in[23];
    const float* fc2_w    = (const float*)d_in[24];
    const float* fc2_b    = (const float*)d_in[25];

    char* p = (char*)d_ws;
    auto take = [&](size_t bytes) {
        void* r = (void*)p;
        p += (bytes + 255) & ~(size_t)255;
        return r;
    };
    float* h1     = (float*)take((size_t)NN * HD * 4);     // 102.4 MB (shared by branches)
    float* ax_c   = (float*)take((size_t)NN * 8 * 4);
    float* ax_s   = (float*)take((size_t)NN * 8 * 4);
    int*   deg_c  = (int*)  take((size_t)NN * 4);          // contiguous with deg_s (one memset)
    int*   deg_s  = (int*)  take((size_t)NN * 4);
    float* dinv_c = (float*)take((size_t)NN * 4);
    float* dinv_s = (float*)take((size_t)NN * 4);
    int*   offs_c = (int*)  take((size_t)(NN + 1) * 4);
    int*   offs_s = (int*)  take((size_t)(NN + 1) * 4);
    int*   cur_c  = (int*)  take((size_t)NN * 4);
    int*   cur_s  = (int*)  take((size_t)NN * 4);
    int*   csr_c  = (int*)  take((size_t)NE * 4);
    int*   csr_s  = (int*)  take((size_t)NE * 4);
    int*   bsum_c = (int*)  take((size_t)NB * 4);
    int*   bsum_s = (int*)  take((size_t)NB * 4);
    float* pool_c = (float*)take((size_t)NG * HD * 4);     // contiguous region: pool_c..cnt_s
    float* pool_s = (float*)take((size_t)NG * HD * 4);
    int*   cnt_c  = (int*)  take((size_t)NG * 4);
    int*   cnt_s  = (int*)  take((size_t)NG * 4);
    (void)ws_size; (void)in_sizes; (void)n_in; (void)out_size;

    hipMemsetAsync(deg_c, 0, (size_t)2 * NN * 4, stream);                       // deg_c + deg_s
    hipMemsetAsync(pool_c, 0, ((size_t)2 * NG * HD + 2 * NG) * 4, stream);      // pools + cnts

    const int* src_c = ei_c;           const int* dst_c = ei_c + NE;
    const int* src_s = ei_s;           const int* dst_s = ei_s + NE;

    // ---- merged prep (both branches in each launch) ----
    k_deg2  <<<(2 * NE + 255) / 256, 256, 0, stream>>>(dst_c, dst_s, deg_c, deg_s);
    k_cntm  <<<(2 * NN + 255) / 256, 256, 0, stream>>>(batch_c, batch_s, cnt_c, cnt_s);
    k_scan1m<<<2 * NB, 256, 0, stream>>>(deg_c, deg_s, bsum_c, bsum_s, dinv_c, dinv_s);
    k_scan2m<<<2, 256, 0, stream>>>(bsum_c, bsum_s);
    k_scan3m<<<2 * NB, 256, 0, stream>>>(deg_c, deg_s, bsum_c, bsum_s,
                                         offs_c, offs_s, cur_c, cur_s);
    k_fillm <<<(2 * NE + 255) / 256, 256, 0, stream>>>(src_c, dst_c, src_s, dst_s,
                                                       cur_c, cur_s, csr_c, csr_s);
    k_aggxm <<<2 * NN * 8 / 256, 256, 0, stream>>>(x_c, x_s, dinv_c, dinv_s,
                                                   offs_c, offs_s, csr_c, csr_s, ax_c, ax_s);

    // ---- branch c ----
    k_gemm1m<<<NN * 32 / 256, 256, 0, stream>>>(ax_c, Wc0, bc0, bnc_g, bnc_b, bnc_m, bnc_v, h1);
    k_agp   <<<NN / 64, 256, 0, stream>>>(h1, dinv_c, offs_c, csr_c, batch_c,
                                          Wc1, bc1, bnc_g + HD, bnc_b + HD, bnc_m + HD, bnc_v + HD,
                                          pool_c);
    // ---- branch s ----
    k_gemm1m<<<NN * 32 / 256, 256, 0, stream>>>(ax_s, Ws0, bs0, bns_g, bns_b, bns_m, bns_v, h1);
    k_agp   <<<NN / 64, 256, 0, stream>>>(h1, dinv_s, offs_s, csr_s, batch_s,
                                          Ws1, bs1, bns_g + HD, bns_b + HD, bns_m + HD, bns_v + HD,
                                          pool_s);

    k_mlp<<<NG / GPB, 128, 0, stream>>>(pool_c, pool_s, cnt_c, cnt_s,
                                        fc1_w, fc1_b, fc2_w, fc2_b, (float*)d_out);
}